// Round 24
// baseline (164.661 us; speedup 1.0000x reference)
//
#include <hip/hip_runtime.h>

typedef __bf16 bf16_t;
typedef __bf16 bf16x8 __attribute__((ext_vector_type(8)));
typedef __bf16 bf16x4v __attribute__((ext_vector_type(4)));
typedef float f32x4 __attribute__((ext_vector_type(4)));

#define MFMA16(a, b, c) __builtin_amdgcn_mfma_f32_16x16x32_bf16((a), (b), (c), 0, 0, 0)

// problem constants
static constexpr int B_ = 8, N_ = 1024, F_ = 512, H_ = 8;
static constexpr int M_ = B_ * N_;  // 8192
static constexpr float LOG2E = 1.4426950408889634f;

__device__ __forceinline__ void gl_lds16(const bf16_t* gsrc, bf16_t* ldst) {
  __builtin_amdgcn_global_load_lds(
      (const __attribute__((address_space(1))) void*)gsrc,
      (__attribute__((address_space(3))) void*)ldst, 16, 0, 0);
}

__device__ __forceinline__ float gelu_tanh(float u) {
  float g = 0.7978845608028654f * fmaf(0.044715f * u * u, u, u);
  float e = __expf(2.f * g);
  float t = 1.f - 2.f / (e + 1.f);
  return 0.5f * u * (1.f + t);
}

// ---------------- merged prep kernel (single launch, role by blockIdx.x) ------
struct PrepArgs {
  const float *features, *geometry;
  const float *wq, *wk, *wv, *wo, *op_w;
  const float *gq_w, *gk_w, *gv_w;
  const float *bq, *bk, *bv, *gq_b, *gv_b;
  const float *d1w, *d1b, *d2w, *d2b;
  bf16_t *featBF, *geomBF, *WqkvT, *GqvT2, *WoT, *OpT;
  float *bqkv, *gqvb2, *dlut;
};

static constexpr int PR_C0 = 4096;              // cast features
static constexpr int PR_C1 = PR_C0 + 1024;      // cast geometry
static constexpr int PR_WQ = PR_C1 + 256;
static constexpr int PR_WK = PR_WQ + 256;
static constexpr int PR_WV = PR_WK + 256;
static constexpr int PR_WO = PR_WV + 256;
static constexpr int PR_OP = PR_WO + 256;
static constexpr int PR_GVT = PR_OP + 64;       // transpose gv_w -> GqvT2[128:640)
static constexpr int PR_WEFF = PR_GVT + 4;      // WeffT -> GqvT2[0:128)
static constexpr int PR_BEFF = PR_WEFF + 1;     // beff -> gqvb2[0:128)
static constexpr int PR_B1 = PR_BEFF + 6;       // concat bqkv (1536)
static constexpr int PR_B2 = PR_B1 + 2;         // gv_b -> gqvb2[128:640)
static constexpr int PR_LUT = PR_B2 + 16;       // dist LUT
static constexpr int PR_TOTAL = PR_LUT;

__device__ __forceinline__ void prep_cast(const float* __restrict__ in,
                                          bf16_t* __restrict__ out, int blk) {
  int i = blk * 256 + threadIdx.x;
  float4 v = ((const float4*)in)[i];
  bf16x4v o;
  o[0] = (bf16_t)v.x; o[1] = (bf16_t)v.y; o[2] = (bf16_t)v.z; o[3] = (bf16_t)v.w;
  ((bf16x4v*)out)[i] = o;
}

__device__ __forceinline__ void prep_transpose(const float* __restrict__ W,
                                               bf16_t* __restrict__ Wt,
                                               int K, int N, int ldo, int idx,
                                               float (*t)[33]) {
  const int bx = idx & 15, by = idx >> 4;
  const int kb = by * 32, cb = bx * 32;
  const int tx = threadIdx.x & 31, ty = threadIdx.x >> 5;
#pragma unroll
  for (int i = 0; i < 4; ++i)
    t[ty * 4 + i][tx] = W[(long)(kb + ty * 4 + i) * N + cb + tx];
  __syncthreads();
#pragma unroll
  for (int i = 0; i < 4; ++i)
    Wt[(long)(cb + ty * 4 + i) * ldo + kb + tx] = (bf16_t)t[tx][ty * 4 + i];
}

__device__ __forceinline__ bf16x8 cvt2x4(float4 a, float4 b) {
  bf16x8 v;
  v[0] = (bf16_t)a.x; v[1] = (bf16_t)a.y; v[2] = (bf16_t)a.z; v[3] = (bf16_t)a.w;
  v[4] = (bf16_t)b.x; v[5] = (bf16_t)b.y; v[6] = (bf16_t)b.z; v[7] = (bf16_t)b.w;
  return v;
}

__global__ __launch_bounds__(256) void k_prep(PrepArgs p) {
  __shared__ alignas(16) char psh[16384];
  float (*tsh)[33] = (float (*)[33])psh;
  const int blk = blockIdx.x;
  if (blk < PR_C0) {
    prep_cast(p.features, p.featBF, blk);
  } else if (blk < PR_C1) {
    prep_cast(p.geometry, p.geomBF, blk - PR_C0);
  } else if (blk < PR_WQ) {
    prep_transpose(p.wq, p.WqkvT, 512, 512, 512, blk - PR_C1, tsh);
  } else if (blk < PR_WK) {
    prep_transpose(p.wk, p.WqkvT + 512 * 512, 512, 512, 512, blk - PR_WQ, tsh);
  } else if (blk < PR_WV) {
    prep_transpose(p.wv, p.WqkvT + 1024 * 512, 512, 512, 512, blk - PR_WK, tsh);
  } else if (blk < PR_WO) {
    prep_transpose(p.wo, p.WoT, 512, 512, 512, blk - PR_WV, tsh);
  } else if (blk < PR_OP) {
    prep_transpose(p.op_w, p.OpT, 512, 512, 512, blk - PR_WO, tsh);
  } else if (blk < PR_GVT) {
    prep_transpose(p.gv_w, p.GqvT2 + 128 * 128, 128, 512, 128, blk - PR_OP, tsh);
  } else if (blk < PR_WEFF) {
    // WeffT[g][h] = sum_f gk_w[g][f]*gq_w[h][f]  (64x64 tile per block)
    bf16_t (*As)[64] = (bf16_t (*)[64])psh;
    bf16_t (*Bs)[64] = (bf16_t (*)[64])(psh + 8192);
    const int wb = blk - PR_GVT;
    const int gBrow = (wb >> 1) * 64;
    const int hBcol = (wb & 1) * 64;
    const int tid = threadIdx.x;
    const int w4 = tid >> 6, lane = tid & 63;
    const int lr = lane & 15, lg = lane >> 4;
    const int wr = w4 >> 1, wc = w4 & 1;
    const int srow = tid >> 2, scol = (tid & 3) << 4;
    f32x4 zero = {0.f, 0.f, 0.f, 0.f};
    f32x4 acc[2][2] = {{zero, zero}, {zero, zero}};
    for (int f0 = 0; f0 < 512; f0 += 64) {
#pragma unroll
      for (int hh = 0; hh < 2; ++hh) {
        const long offA = (long)(gBrow + srow) * 512 + f0 + scol + hh * 8;
        float4 a0 = *(const float4*)(p.gk_w + offA);
        float4 a1 = *(const float4*)(p.gk_w + offA + 4);
        *(bf16x8*)(&As[srow][scol + hh * 8]) = cvt2x4(a0, a1);
        const long offB = (long)(hBcol + srow) * 512 + f0 + scol + hh * 8;
        float4 b0 = *(const float4*)(p.gq_w + offB);
        float4 b1 = *(const float4*)(p.gq_w + offB + 4);
        *(bf16x8*)(&Bs[srow][scol + hh * 8]) = cvt2x4(b0, b1);
      }
      __syncthreads();
#pragma unroll
      for (int ks = 0; ks < 2; ++ks) {
        bf16x8 a[2], b[2];
#pragma unroll
        for (int i = 0; i < 2; ++i) {
          a[i] = *(const bf16x8*)(&As[wr * 32 + i * 16 + lr][ks * 32 + lg * 8]);
          b[i] = *(const bf16x8*)(&Bs[wc * 32 + i * 16 + lr][ks * 32 + lg * 8]);
        }
#pragma unroll
        for (int mf = 0; mf < 2; ++mf)
#pragma unroll
          for (int nf = 0; nf < 2; ++nf)
            acc[mf][nf] = MFMA16(a[mf], b[nf], acc[mf][nf]);
      }
      __syncthreads();
    }
#pragma unroll
    for (int mf = 0; mf < 2; ++mf)
#pragma unroll
      for (int nf = 0; nf < 2; ++nf)
#pragma unroll
        for (int rg = 0; rg < 4; ++rg) {
          const int row = gBrow + wr * 32 + mf * 16 + lg * 4 + rg;
          const int col = hBcol + wc * 32 + nf * 16 + lr;
          p.GqvT2[(long)row * 128 + col] = (bf16_t)acc[mf][nf][rg];
        }
  } else if (blk < PR_BEFF) {
    const int g = threadIdx.x;
    if (g < 128) {
      float s = 0.f;
      for (int f = 0; f < 512; ++f) s = fmaf(p.gq_b[f], p.gk_w[(long)g * 512 + f], s);
      p.gqvb2[g] = s;
    }
  } else if (blk < PR_B1) {
    int i = (blk - PR_BEFF) * 256 + threadIdx.x;
    p.bqkv[i] = i < 512 ? p.bq[i] : (i < 1024 ? p.bk[i - 512] : p.bv[i - 1024]);
  } else if (blk < PR_B2) {
    int i = (blk - PR_B1) * 256 + threadIdx.x;
    p.gqvb2[128 + i] = p.gv_b[i];
  } else {
    int i = (blk - PR_B2) * 256 + threadIdx.x;
    float d = (i + 0.5f) * (16.f / 4096.f);
    float s = 0.f;
#pragma unroll
    for (int h = 0; h < 8; ++h) s += p.d2b[h];
    s *= 0.125f;
#pragma unroll
    for (int j = 0; j < 8; ++j) {
      float w2 = 0.f;
#pragma unroll
      for (int h = 0; h < 8; ++h) w2 += p.d2w[j * 8 + h];
      s = fmaf(gelu_tanh(fmaf(d, p.d1w[j], p.d1b[j])), w2 * 0.125f, s);
    }
    p.dlut[i] = s;
  }
}

// ---------------- GEMM args ----------------
struct GemmArgs {
  const bf16_t* A; const bf16_t* Bt;
  const float* bias; const float* addSrc; const bf16_t* addSrcB;
  const float* coords; const float* lut;
  float* outF; bf16_t* outB;
  bf16_t* outT;      // if set: tiles with cBase>=vtileFrom write TRANSPOSED to outT
  int vtileFrom;
  long strideAb; long strideBb;
  int lda, ldb, K, ldout;
  float scale;
};

// ---- 128x128 core (plain epilogue + optional transposed V write) ----
__device__ __forceinline__ void gemm128_core(const GemmArgs& g, int mBase, int cBase,
                                             bf16_t (*As)[64], bf16_t (*Bs)[64]) {
  const int tid = threadIdx.x;
  const int w = tid >> 6, lane = tid & 63;
  const int lr = lane & 15, lg = lane >> 4;
  const int wr = w >> 1, wc = w & 1;
  const int batch = mBase >> 10;

  const int srow = lane >> 3;
  const int scol = (lane & 7) * 8;
  const bf16_t* Ag = g.A + (long)batch * g.strideAb +
                     (long)((mBase & 1023) + w * 32 + srow) * g.lda + scol;
  const bf16_t* Bg = g.Bt + (long)batch * g.strideBb +
                     (long)(cBase + w * 32 + srow) * g.ldb + scol;
  bf16_t* Al = &As[w * 32][0];
  bf16_t* Bl = &Bs[w * 32][0];

  f32x4 zero = {0.f, 0.f, 0.f, 0.f};
  f32x4 acc[4][4];
#pragma unroll
  for (int i = 0; i < 4; ++i)
#pragma unroll
    for (int j = 0; j < 4; ++j) acc[i][j] = zero;

  for (int k0 = 0; k0 < g.K; k0 += 64) {
#pragma unroll
    for (int is = 0; is < 4; ++is) {
      gl_lds16(Ag + (long)(is * 8) * g.lda + k0, Al + is * 8 * 64);
      gl_lds16(Bg + (long)(is * 8) * g.ldb + k0, Bl + is * 8 * 64);
    }
    __syncthreads();
#pragma unroll
    for (int ks = 0; ks < 2; ++ks) {
      bf16x8 a[4], b[4];
#pragma unroll
      for (int i = 0; i < 4; ++i) {
        a[i] = *(const bf16x8*)(&As[wr * 64 + i * 16 + lr][ks * 32 + lg * 8]);
        b[i] = *(const bf16x8*)(&Bs[wc * 64 + i * 16 + lr][ks * 32 + lg * 8]);
      }
#pragma unroll
      for (int mf = 0; mf < 4; ++mf)
#pragma unroll
        for (int nf = 0; nf < 4; ++nf)
          acc[mf][nf] = MFMA16(a[mf], b[nf], acc[mf][nf]);
    }
    __syncthreads();
  }

  const int c0 = cBase + wc * 64;
  float bias4[4];
#pragma unroll
  for (int nf = 0; nf < 4; ++nf)
    bias4[nf] = g.bias ? g.bias[c0 + nf * 16 + lr] : 0.f;
  const bool vtile = (g.outT != nullptr) && (cBase >= g.vtileFrom);
#pragma unroll
  for (int mf = 0; mf < 4; ++mf) {
    const int r0 = mBase + wr * 64 + mf * 16 + lg * 4;
    const int r0b = r0 & 1023;
#pragma unroll
    for (int nf = 0; nf < 4; ++nf) {
      const int c = c0 + nf * 16 + lr;
      if (vtile) {
        bf16x4v vv;
#pragma unroll
        for (int rg = 0; rg < 4; ++rg)
          vv[rg] = (bf16_t)(acc[mf][nf][rg] * g.scale + bias4[nf]);
        *(bf16x4v*)(&g.outT[((long)batch * 512 + (c - g.vtileFrom)) * 1024 + r0b]) = vv;
      } else {
#pragma unroll
        for (int rg = 0; rg < 4; ++rg) {
          const int r = r0 + rg;
          float v = acc[mf][nf][rg] * g.scale + bias4[nf];
          if (g.addSrc) v += g.addSrc[(long)r * g.ldout + c];
          const long oi = (long)r * g.ldout + c;
          if (g.outF) g.outF[oi] = v;
          if (g.outB) g.outB[oi] = (bf16_t)v;
        }
      }
    }
  }
}

// dual-role 128x128 GEMM (flattened: 768 QKV blocks + 320 GQV2 blocks)
__global__ __launch_bounds__(256) void k_gemm128_dual(GemmArgs g1, GemmArgs g2) {
  __shared__ alignas(16) bf16_t As[128][64];
  __shared__ alignas(16) bf16_t Bs[128][64];
  const int bx = blockIdx.x;
  if (bx < 768) {
    gemm128_core(g1, (bx / 12) * 128, (bx % 12) * 128, As, Bs);
  } else {
    const int i = bx - 768;
    gemm128_core(g2, (i / 5) * 128, (i % 5) * 128, As, Bs);
  }
}

// ---- 128x128 core, dist-LUT + exp2 epilogue -> bf16 Pun (unnormalized p) ----
__device__ __forceinline__ void gemm128_dist(const GemmArgs& g, int mBase, int cBase,
                                             char* smemc) {
  bf16_t (*As)[64] = (bf16_t (*)[64])smemc;
  bf16_t (*Bs)[64] = (bf16_t (*)[64])(smemc + 16384);
  bf16_t* Lut = (bf16_t*)(smemc + 32768);
  const int tid = threadIdx.x;
  const int w = tid >> 6, lane = tid & 63;
  const int lr = lane & 15, lg = lane >> 4;
  const int wr = w >> 1, wc = w & 1;
  const int batch = mBase >> 10;

  {
    const float4* src = (const float4*)g.lut;
#pragma unroll
    for (int i = 0; i < 4; ++i) {
      float4 v = src[tid + i * 256];
      bf16x4v o;
      o[0] = (bf16_t)(v.x * LOG2E); o[1] = (bf16_t)(v.y * LOG2E);
      o[2] = (bf16_t)(v.z * LOG2E); o[3] = (bf16_t)(v.w * LOG2E);
      ((bf16x4v*)Lut)[tid + i * 256] = o;
    }
  }

  const int srow = lane >> 3;
  const int scol = (lane & 7) * 8;
  const bf16_t* Ag = g.A + (long)batch * g.strideAb +
                     (long)((mBase & 1023) + w * 32 + srow) * g.lda + scol;
  const bf16_t* Bg = g.Bt + (long)batch * g.strideBb +
                     (long)(cBase + w * 32 + srow) * g.ldb + scol;
  bf16_t* Al = &As[w * 32][0];
  bf16_t* Bl = &Bs[w * 32][0];

  f32x4 zero = {0.f, 0.f, 0.f, 0.f};
  f32x4 acc[4][4];
#pragma unroll
  for (int i = 0; i < 4; ++i)
#pragma unroll
    for (int j = 0; j < 4; ++j) acc[i][j] = zero;

  for (int k0 = 0; k0 < g.K; k0 += 64) {
#pragma unroll
    for (int is = 0; is < 4; ++is) {
      gl_lds16(Ag + (long)(is * 8) * g.lda + k0, Al + is * 8 * 64);
      gl_lds16(Bg + (long)(is * 8) * g.ldb + k0, Bl + is * 8 * 64);
    }
    __syncthreads();
#pragma unroll
    for (int ks = 0; ks < 2; ++ks) {
      bf16x8 a[4], b[4];
#pragma unroll
      for (int i = 0; i < 4; ++i) {
        a[i] = *(const bf16x8*)(&As[wr * 64 + i * 16 + lr][ks * 32 + lg * 8]);
        b[i] = *(const bf16x8*)(&Bs[wc * 64 + i * 16 + lr][ks * 32 + lg * 8]);
      }
#pragma unroll
      for (int mf = 0; mf < 4; ++mf)
#pragma unroll
        for (int nf = 0; nf < 4; ++nf)
          acc[mf][nf] = MFMA16(a[mf], b[nf], acc[mf][nf]);
    }
    __syncthreads();
  }

  const int c0 = cBase + wc * 64;
  float ckx[4], cky[4], ckz[4];
#pragma unroll
  for (int nf = 0; nf < 4; ++nf) {
    const float* ck = g.coords + ((long)batch * 1024 + c0 + nf * 16 + lr) * 3;
    ckx[nf] = ck[0]; cky[nf] = ck[1]; ckz[nf] = ck[2];
  }
#pragma unroll
  for (int mf = 0; mf < 4; ++mf) {
    const int r0 = mBase + wr * 64 + mf * 16 + lg * 4;
    float cqx[4], cqy[4], cqz[4];
#pragma unroll
    for (int rg = 0; rg < 4; ++rg) {
      const float* cq = g.coords + ((long)batch * 1024 + ((r0 + rg) & 1023)) * 3;
      cqx[rg] = cq[0]; cqy[rg] = cq[1]; cqz[rg] = cq[2];
    }
#pragma unroll
    for (int nf = 0; nf < 4; ++nf) {
      const int c = c0 + nf * 16 + lr;
#pragma unroll
      for (int rg = 0; rg < 4; ++rg) {
        const int r = r0 + rg;
        float v = acc[mf][nf][rg] * g.scale;  // scale = 0.125*log2e
        float dx = cqx[rg] - ckx[nf], dy = cqy[rg] - cky[nf], dz = cqz[rg] - ckz[nf];
        float d = sqrtf(fmaxf(dx * dx + dy * dy + dz * dz, 1e-12f));
        int idx = (int)(d * 256.f);
        idx = idx > 4095 ? 4095 : idx;
        g.outB[(long)r * g.ldout + c] = (bf16_t)exp2f(v + (float)Lut[idx]);
      }
    }
  }
}

// ---- flash attention core, QBLK=128, 3-deep KV pipeline (counted vmcnt) ----
// Buffers: buf i at smemc+i*16384 (K 8KB | V 8KB); P relay at smemc+49152 (8KB).
// Per tile: s_waitcnt vmcnt(4) (tile t done, t+1 in flight) -> raw s_barrier
// (no implicit vmcnt(0) drain) -> stage t+2 -> compute t. Loads get ~2 tiles
// of compute to land; the m97-style per-tile drain is eliminated.
__device__ __forceinline__ void flash_core(const bf16_t* __restrict__ QKV,
                                           const bf16_t* __restrict__ Vt,
                                           bf16_t* __restrict__ fatt,
                                           int qx, int bh, char* smemc) {
  char* Plb = smemc + 49152;                                   // 8 KB
  const int wave = threadIdx.x >> 6, lane = threadIdx.x & 63;
  const int lr = lane & 15, lg = (lane >> 4) & 3;
  const int b = bh >> 3, h = bh & 7;
  const int qbase = qx * 128 + wave * 32;

  const bf16_t* Qb = QKV + (long)b * 1024 * 1536 + h * 64;
  const bf16_t* Kb = Qb + 512;
  const bf16_t* Vg = Vt + ((long)b * 512 + h * 64) * 1024;

  constexpr float SCL = 0.18033688011112042f;  // 0.125 * log2(e)
  bf16x8 q_[2][2];
#pragma unroll
  for (int qf = 0; qf < 2; ++qf)
#pragma unroll
    for (int dh = 0; dh < 2; ++dh) {
      bf16x8 raw = *(const bf16x8*)(Qb + (long)(qbase + qf * 16 + lr) * 1536 +
                                    dh * 32 + lg * 8);
#pragma unroll
      for (int j = 0; j < 8; ++j) q_[qf][dh][j] = (bf16_t)((float)raw[j] * SCL);
    }
  bf16x8 onesb;
#pragma unroll
  for (int j = 0; j < 8; ++j) onesb[j] = (bf16_t)1.0f;

  const int srow = lane >> 3;
  const int scol = (((lane & 7) ^ srow) << 3);
  const bf16_t* KgB = Kb + (long)(wave * 16 + srow) * 1536 + scol;
  const bf16_t* VgB = Vg + (long)(wave * 16 + srow) * 1024 + scol;

  auto stage = [&](char* buf, int kt) {
    bf16_t* Kd = (bf16_t*)buf;
    bf16_t* Vd = (bf16_t*)(buf + 8192);
#pragma unroll
    for (int i = 0; i < 2; ++i) {
      gl_lds16(KgB + (long)(kt + i * 8) * 1536, Kd + (wave * 16 + i * 8) * 64);
      gl_lds16(VgB + (long)(i * 8) * 1024 + kt, Vd + (wave * 16 + i * 8) * 64);
    }
  };

  f32x4 zero = {0.f, 0.f, 0.f, 0.f};
  f32x4 oacc[2][4] = {{zero, zero, zero, zero}, {zero, zero, zero, zero}};
  f32x4 oL[2] = {zero, zero};
  const int swz = (lr & 7) << 4;        // K/V tile swizzle
  const int swp = (lr & 6) << 3;        // P buffer swizzle (bits 4-5)
  char* PlW = Plb + wave * 2048;

  char* p0 = smemc;
  char* p1 = smemc + 16384;
  char* p2 = smemc + 32768;
  stage(p0, 0);
  stage(p1, 64);

  auto compute = [&](const char* KB, const char* VB) __attribute__((always_inline)) {
#pragma unroll
    for (int kk = 0; kk < 2; ++kk) {
      f32x4 S[2][2];
      __builtin_amdgcn_s_setprio(1);
#pragma unroll
      for (int kh = 0; kh < 2; ++kh) {
        const int row = kk * 32 + kh * 16 + lr;
        bf16x8 k0 = *(const bf16x8*)(KB + row * 128 + ((lg * 16) ^ swz));
        bf16x8 k1 = *(const bf16x8*)(KB + row * 128 + ((64 + lg * 16) ^ swz));
#pragma unroll
        for (int qf = 0; qf < 2; ++qf) {
          f32x4 tt = MFMA16(k0, q_[qf][0], zero);
          S[qf][kh] = MFMA16(k1, q_[qf][1], tt);
        }
      }
      __builtin_amdgcn_s_setprio(0);
#pragma unroll
      for (int qf = 0; qf < 2; ++qf)
#pragma unroll
        for (int kh = 0; kh < 2; ++kh) {
          bf16x4v pp;
#pragma unroll
          for (int r = 0; r < 4; ++r) pp[r] = (bf16_t)exp2f(S[qf][kh][r]);
          *(bf16x4v*)(PlW + qf * 1024 + lr * 64 + ((kh * 32 + lg * 8) ^ swp)) = pp;
        }
      asm volatile("s_waitcnt lgkmcnt(0)" ::: "memory");
      __builtin_amdgcn_sched_barrier(0);
      const bf16x8 pa0 = *(const bf16x8*)(PlW + lr * 64 + ((lg * 16) ^ swp));
      const bf16x8 pa1 = *(const bf16x8*)(PlW + 1024 + lr * 64 + ((lg * 16) ^ swp));
      __builtin_amdgcn_s_setprio(1);
#pragma unroll
      for (int ct = 0; ct < 4; ++ct) {
        const int vrow = ct * 16 + lr;
        bf16x8 vf = *(const bf16x8*)(VB + vrow * 128 + ((kk * 64 + lg * 16) ^ swz));
        oacc[0][ct] = MFMA16(pa0, vf, oacc[0][ct]);
        oacc[1][ct] = MFMA16(pa1, vf, oacc[1][ct]);
      }
      oL[0] = MFMA16(pa0, onesb, oL[0]);
      oL[1] = MFMA16(pa1, onesb, oL[1]);
      __builtin_amdgcn_s_setprio(0);
    }
  };

  for (int t = 0; t < 15; ++t) {
    asm volatile("s_waitcnt vmcnt(4)" ::: "memory");
    __builtin_amdgcn_s_barrier();
    asm volatile("" ::: "memory");
    if (t + 2 < 16) stage(p2, (t + 2) * 64);
    compute(p0, p0 + 8192);
    char* tmp = p0; p0 = p1; p1 = p2; p2 = tmp;
  }
  // last tile: drain all remaining loads
  asm volatile("s_waitcnt vmcnt(0)" ::: "memory");
  __builtin_amdgcn_s_barrier();
  asm volatile("" ::: "memory");
  compute(p0, p0 + 8192);

#pragma unroll
  for (int qf = 0; qf < 2; ++qf)
#pragma unroll
    for (int r = 0; r < 4; ++r) {
      float inv = 1.f / oL[qf][r];
      int q = qbase + qf * 16 + lg * 4 + r;
      bf16_t* orow = fatt + ((long)b * 1024 + q) * 512 + h * 64;
#pragma unroll
      for (int ct = 0; ct < 4; ++ct)
        orow[ct * 16 + lr] = (bf16_t)(oacc[qf][ct][r] * inv);
    }
}

// ---- fused: gsc (blocks 0..511, K=128 low-rank) + flash QBLK=128 (512..1023) --
__global__ __launch_bounds__(256) void k_gsc_flash(GemmArgs g,
                                                   const bf16_t* __restrict__ QKV,
                                                   const bf16_t* __restrict__ Vt,
                                                   bf16_t* __restrict__ fatt) {
  __shared__ alignas(16) char smem[57344];
  const int bx = blockIdx.x;
  if (bx < 512) {
    gemm128_dist(g, (bx >> 3) * 128, (bx & 7) * 128, smem);
  } else {
    const int fid = bx - 512;
    flash_core(QKV, Vt, fatt, fid & 7, fid >> 3, smem);
  }
}

// ---- 64x64 tile K-loop: 4 waves, each a 32x32 quadrant (acc[2][2]) ----
template <int RSUM>
__device__ __forceinline__ void m64_loop(const GemmArgs& g, int mBase, int cBase,
                                         bf16_t (*As)[64], bf16_t (*Bs)[64],
                                         f32x4 (*acc)[2], f32x4* lacc) {
  const int tid = threadIdx.x;
  const int w = tid >> 6, lane = tid & 63;
  const int lr = lane & 15, lg = lane >> 4;
  const int wr = w >> 1, wc = w & 1;
  const int batch = mBase >> 10;

  const int srow = lane >> 3;
  const int scol = (lane & 7) * 8;
  const bf16_t* Ag = g.A + (long)batch * g.strideAb +
                     (long)((mBase & 1023) + w * 16 + srow) * g.lda + scol;
  const bf16_t* Bg = g.Bt + (long)batch * g.strideBb +
                     (long)(cBase + w * 16 + srow) * g.ldb + scol;
  bf16_t* Al = &As[w * 16][0];
  bf16_t* Bl = &Bs[w * 16][0];

  bf16x8 onesb;
#pragma unroll
  for (int j = 0; j < 8; ++j) onesb[j] = (bf16_t)1.0f;

  for (int k0 = 0; k0 < g.K; k0 += 64) {
#pragma unroll
    for (int is = 0; is < 2; ++is) {
      gl_lds16(Ag + (long)(is * 8) * g.lda + k0, Al + is * 8 * 64);
      gl_lds16(Bg + (long)(is * 8) * g.ldb + k0, Bl + is * 8 * 64);
    }
    __syncthreads();
#pragma unroll
    for (int ks = 0; ks < 2; ++ks) {
      bf16x8 a[2], b[2];
#pragma unroll
      for (int i = 0; i < 2; ++i) {
        a[i] = *(const bf16x8*)(&As[wr * 32 + i * 16 + lr][ks * 32 + lg * 8]);
        b[i] = *(const bf16x8*)(&Bs[wc * 32 + i * 16 + lr][ks * 32 + lg * 8]);
      }
#pragma unroll
      for (int mf = 0; mf < 2; ++mf)
#pragma unroll
        for (int nf = 0; nf < 2; ++nf)
          acc[mf][nf] = MFMA16(a[mf], b[nf], acc[mf][nf]);
      if constexpr (RSUM) {
#pragma unroll
        for (int mf = 0; mf < 2; ++mf)
          lacc[mf] = MFMA16(a[mf], onesb, lacc[mf]);
      }
    }
    __syncthreads();
  }
}

// ---- plain 64x64 GEMM (4 blocks/CU for the latency-bound tail) ----
__global__ __launch_bounds__(256) void k_gemm_m64(GemmArgs g) {
  __shared__ alignas(16) bf16_t As[64][64];
  __shared__ alignas(16) bf16_t Bs[64][64];
  const int tid = threadIdx.x;
  const int w = tid >> 6, lane = tid & 63;
  const int lr = lane & 15, lg = lane >> 4;
  const int wr = w >> 1, wc = w & 1;
  const int mBase = blockIdx.y * 64, cBase = blockIdx.x * 64;

  f32x4 zero = {0.f, 0.f, 0.f, 0.f};
  f32x4 acc[2][2] = {{zero, zero}, {zero, zero}};
  m64_loop<0>(g, mBase, cBase, As, Bs, acc, nullptr);

  const int c0 = cBase + wc * 32;
  float bias2[2];
#pragma unroll
  for (int nf = 0; nf < 2; ++nf)
    bias2[nf] = g.bias ? g.bias[c0 + nf * 16 + lr] : 0.f;
#pragma unroll
  for (int mf = 0; mf < 2; ++mf) {
    const int r0 = mBase + wr * 32 + mf * 16 + lg * 4;
#pragma unroll
    for (int nf = 0; nf < 2; ++nf) {
      const int c = c0 + nf * 16 + lr;
#pragma unroll
      for (int rg = 0; rg < 4; ++rg) {
        const int r = r0 + rg;
        float v = acc[mf][nf][rg] * g.scale + bias2[nf];
        const long oi = (long)r * g.ldout + c;
        if (g.outF) g.outF[oi] = v;
        if (g.outB) g.outB[oi] = (bf16_t)v;
      }
    }
  }
}

// ---- fused comb: combB = (Pun @ GV)/rowsum(Pun) + fatt @ Wo + bo ----
__global__ __launch_bounds__(256) void k_comb(GemmArgs gF, GemmArgs gG,
                                              bf16_t* __restrict__ outB) {
  __shared__ alignas(16) bf16_t As[64][64];
  __shared__ alignas(16) bf16_t Bs[64][64];
  const int tid = threadIdx.x;
  const int w = tid >> 6, lane = tid & 63;
  const int lr = lane & 15, lg = lane >> 4;
  const int wr = w >> 1, wc = w & 1;
  const int mBase = blockIdx.y * 64, cBase = blockIdx.x * 64;

  f32x4 zero = {0.f, 0.f, 0.f, 0.f};
  f32x4 acc1[2][2] = {{zero, zero}, {zero, zero}};
  f32x4 acc2[2][2] = {{zero, zero}, {zero, zero}};
  f32x4 lacc[2] = {zero, zero};
  m64_loop<0>(gF, mBase, cBase, As, Bs, acc1, nullptr);
  m64_loop<1>(gG, mBase, cBase, As, Bs, acc2, lacc);

  const int c0 = cBase + wc * 32;
  float bias2[2];
#pragma unroll
  for (int nf = 0; nf < 2; ++nf)
    bias2[nf] = gF.bias[c0 + nf * 16 + lr];
#pragma unroll
  for (int mf = 0; mf < 2; ++mf) {
    const int r0 = mBase + wr * 32 + mf * 16 + lg * 4;
    float linv[4];
#pragma unroll
    for (int rg = 0; rg < 4; ++rg) linv[rg] = 1.f / lacc[mf][rg];
#pragma unroll
    for (int nf = 0; nf < 2; ++nf) {
      const int c = c0 + nf * 16 + lr;
#pragma unroll
      for (int rg = 0; rg < 4; ++rg) {
        const int r = r0 + rg;
        float v = acc2[mf][nf][rg] * linv[rg] + acc1[mf][nf][rg] + bias2[nf];
        outB[(long)r * 512 + c] = (bf16_t)v;
      }
    }
  }
}

// ---------------- launch ----------------
extern "C" void kernel_launch(void* const* d_in, const int* in_sizes, int n_in,
                              void* d_out, int out_size, void* d_ws, size_t ws_size,
                              hipStream_t stream) {
  const float* features = (const float*)d_in[0];
  const float* geometry = (const float*)d_in[1];
  const float* coords   = (const float*)d_in[2];
  const float* wq = (const float*)d_in[3];  const float* bq = (const float*)d_in[4];
  const float* wk = (const float*)d_in[5];  const float* bk = (const float*)d_in[6];
  const float* wv = (const float*)d_in[7];  const float* bv = (const float*)d_in[8];
  const float* wo = (const float*)d_in[9];  const float* bo = (const float*)d_in[10];
  const float* gq_w = (const float*)d_in[11]; const float* gq_b = (const float*)d_in[12];
  const float* gk_w = (const float*)d_in[13]; const float* gk_b = (const float*)d_in[14];
  const float* gv_w = (const float*)d_in[15]; const float* gv_b = (const float*)d_in[16];
  const float* d1_w = (const float*)d_in[17]; const float* d1_b = (const float*)d_in[18];
  const float* d2_w = (const float*)d_in[19]; const float* d2_b = (const float*)d_in[20];
  const float* op_w = (const float*)d_in[21]; const float* op_b = (const float*)d_in[22];
  (void)gk_b;  // row-constant score term: cancels under softmax normalization

  // ---- workspace carve ----
  size_t off = 0;
  auto carve = [&](size_t bytes) {
    void* p = (char*)d_ws + off;
    off += (bytes + 255) & ~(size_t)255;
    return p;
  };
  bf16_t* featBF = (bf16_t*)carve((size_t)M_ * F_ * 2);
  bf16_t* geomBF = (bf16_t*)carve((size_t)M_ * 128 * 2);
  bf16_t* WqkvT  = (bf16_t*)carve((size_t)1536 * 512 * 2);
  bf16_t* GqvT2  = (bf16_t*)carve((size_t)640 * 128 * 2);  // [0:128)=WeffT, [128:640)=gv^T
  bf16_t* WoT    = (bf16_t*)carve((size_t)512 * 512 * 2);
  bf16_t* OpT    = (bf16_t*)carve((size_t)512 * 512 * 2);
  float*  bqkv   = (float*)carve(1536 * 4);
  float*  gqvb2  = (float*)carve(640 * 4);
  float*  dlut   = (float*)carve(4096 * 4);
  bf16_t* QKV    = (bf16_t*)carve((size_t)M_ * 1536 * 2);
  bf16_t* GQeff  = (bf16_t*)carve((size_t)M_ * 128 * 2);
  bf16_t* Vt     = (bf16_t*)carve((size_t)B_ * 512 * 1024 * 2);
  bf16_t* GVt    = (bf16_t*)carve((size_t)B_ * 512 * 1024 * 2);
  bf16_t* Pun    = (bf16_t*)carve((size_t)M_ * 1024 * 2);
  bf16_t* fatt   = (bf16_t*)carve((size_t)M_ * 512 * 2);
  bf16_t* combB  = (bf16_t*)carve((size_t)M_ * 512 * 2);
  if (off > ws_size) return;

  // 0) merged prep (WeffT + beff folded in)
  PrepArgs p;
  p.features = features; p.geometry = geometry;
  p.wq = wq; p.wk = wk; p.wv = wv; p.wo = wo; p.op_w = op_w;
  p.gq_w = gq_w; p.gk_w = gk_w; p.gv_w = gv_w;
  p.bq = bq; p.bk = bk; p.bv = bv; p.gq_b = gq_b; p.gv_b = gv_b;
  p.d1w = d1_w; p.d1b = d1_b; p.d2w = d2_w; p.d2b = d2_b;
  p.featBF = featBF; p.geomBF = geomBF; p.WqkvT = WqkvT; p.GqvT2 = GqvT2;
  p.WoT = WoT; p.OpT = OpT;
  p.bqkv = bqkv; p.gqvb2 = gqvb2; p.dlut = dlut;
  k_prep<<<PR_TOTAL, 256, 0, stream>>>(p);

  auto mk = [](const bf16_t* A, long sAb, int lda, const bf16_t* Bt, long sBb, int ldb,
               int K, const float* bias, const float* addSrc, const bf16_t* addSrcB,
               float* outF, bf16_t* outB, int ldout, float scale,
               const float* coords, const float* lut, bf16_t* outT, int vtileFrom) {
    GemmArgs g;
    g.A = A; g.Bt = Bt; g.bias = bias; g.addSrc = addSrc; g.addSrcB = addSrcB;
    g.coords = coords; g.lut = lut; g.outF = outF; g.outB = outB; g.outT = outT;
    g.vtileFrom = vtileFrom;
    g.strideAb = sAb; g.strideBb = sBb; g.lda = lda; g.ldb = ldb;
    g.K = K; g.ldout = ldout; g.scale = scale;
    return g;
  };

  // 1) QKV (768 blocks) + [GQeff|GV] (320 blocks); V/GV written TRANSPOSED
  k_gemm128_dual<<<1088, 256, 0, stream>>>(
      mk(featBF, (long)1024 * 512, 512, WqkvT, 0, 512, 512,
         bqkv, nullptr, nullptr, nullptr, QKV, 1536, 1.f, nullptr, nullptr, Vt, 1024),
      mk(geomBF, (long)1024 * 128, 128, GqvT2, 0, 128, 128,
         gqvb2, nullptr, nullptr, nullptr, GQeff, 128, 1.f, nullptr, nullptr, GVt, 128));
  // 2) fused: Pun = exp2(GQeff.geom^T*scl + lut) [K=128] + flash (QBLK=128, 3-deep)
  k_gsc_flash<<<1024, 256, 0, stream>>>(
      mk(GQeff, (long)1024 * 128, 128, geomBF, (long)1024 * 128, 128, 128,
         nullptr, nullptr, nullptr, nullptr, Pun, 1024, 0.125f * LOG2E,
         coords, dlut, nullptr, 1 << 30),
      QKV, Vt, fatt);
  // 3) combB = (Pun @ GV)/rowsum(Pun) + fatt @ wo + bo  (fused, 64x64 tiles)
  k_comb<<<dim3(8, 128), 256, 0, stream>>>(
      mk(fatt, (long)1024 * 512, 512, WoT, 0, 512, 512,
         bo, nullptr, nullptr, nullptr, nullptr, 512, 1.f, nullptr, nullptr,
         nullptr, 1 << 30),
      mk(Pun, (long)1024 * 1024, 1024, GVt, (long)512 * 1024, 1024, 1024,
         nullptr, nullptr, nullptr, nullptr, nullptr, 512, 1.f, nullptr, nullptr,
         nullptr, 1 << 30),
      combB);
  // 4) out = combB @ op_w + op_b
  k_gemm_m64<<<dim3(8, 128), 256, 0, stream>>>(
      mk(combB, (long)1024 * 512, 512, OpT, 0, 512, 512,
         op_b, nullptr, nullptr, (float*)d_out, nullptr, 512, 1.f, nullptr, nullptr,
         nullptr, 1 << 30));
}

// Round 25
// 159.975 us; speedup vs baseline: 1.0293x; 1.0293x over previous
//
#include <hip/hip_runtime.h>

typedef __bf16 bf16_t;
typedef __bf16 bf16x8 __attribute__((ext_vector_type(8)));
typedef __bf16 bf16x4v __attribute__((ext_vector_type(4)));
typedef float f32x4 __attribute__((ext_vector_type(4)));

#define MFMA16(a, b, c) __builtin_amdgcn_mfma_f32_16x16x32_bf16((a), (b), (c), 0, 0, 0)

// problem constants
static constexpr int B_ = 8, N_ = 1024, F_ = 512, H_ = 8;
static constexpr int M_ = B_ * N_;  // 8192
static constexpr float LOG2E = 1.4426950408889634f;

__device__ __forceinline__ void gl_lds16(const bf16_t* gsrc, bf16_t* ldst) {
  __builtin_amdgcn_global_load_lds(
      (const __attribute__((address_space(1))) void*)gsrc,
      (__attribute__((address_space(3))) void*)ldst, 16, 0, 0);
}

__device__ __forceinline__ float gelu_tanh(float u) {
  float g = 0.7978845608028654f * fmaf(0.044715f * u * u, u, u);
  float e = __expf(2.f * g);
  float t = 1.f - 2.f / (e + 1.f);
  return 0.5f * u * (1.f + t);
}

// ---------------- merged prep kernel (single launch, role by blockIdx.x) ------
struct PrepArgs {
  const float *features, *geometry;
  const float *wq, *wk, *wv, *wo, *op_w;
  const float *gq_w, *gk_w, *gv_w;
  const float *bq, *bk, *bv, *gq_b, *gv_b;
  const float *d1w, *d1b, *d2w, *d2b;
  bf16_t *featBF, *geomBF, *WqkvT, *GqvT2, *WoT, *OpT;
  float *bqkv, *gqvb2, *dlut;
};

static constexpr int PR_C0 = 4096;              // cast features
static constexpr int PR_C1 = PR_C0 + 1024;      // cast geometry
static constexpr int PR_WQ = PR_C1 + 256;
static constexpr int PR_WK = PR_WQ + 256;
static constexpr int PR_WV = PR_WK + 256;
static constexpr int PR_WO = PR_WV + 256;
static constexpr int PR_OP = PR_WO + 256;
static constexpr int PR_GVT = PR_OP + 64;       // transpose gv_w -> GqvT2[128:640)
static constexpr int PR_WEFF = PR_GVT + 4;      // WeffT -> GqvT2[0:128)
static constexpr int PR_BEFF = PR_WEFF + 1;     // beff -> gqvb2[0:128)
static constexpr int PR_B1 = PR_BEFF + 6;       // concat bqkv (1536)
static constexpr int PR_B2 = PR_B1 + 2;         // gv_b -> gqvb2[128:640)
static constexpr int PR_LUT = PR_B2 + 16;       // dist LUT
static constexpr int PR_TOTAL = PR_LUT;

__device__ __forceinline__ void prep_cast(const float* __restrict__ in,
                                          bf16_t* __restrict__ out, int blk) {
  int i = blk * 256 + threadIdx.x;
  float4 v = ((const float4*)in)[i];
  bf16x4v o;
  o[0] = (bf16_t)v.x; o[1] = (bf16_t)v.y; o[2] = (bf16_t)v.z; o[3] = (bf16_t)v.w;
  ((bf16x4v*)out)[i] = o;
}

__device__ __forceinline__ void prep_transpose(const float* __restrict__ W,
                                               bf16_t* __restrict__ Wt,
                                               int K, int N, int ldo, int idx,
                                               float (*t)[33]) {
  const int bx = idx & 15, by = idx >> 4;
  const int kb = by * 32, cb = bx * 32;
  const int tx = threadIdx.x & 31, ty = threadIdx.x >> 5;
#pragma unroll
  for (int i = 0; i < 4; ++i)
    t[ty * 4 + i][tx] = W[(long)(kb + ty * 4 + i) * N + cb + tx];
  __syncthreads();
#pragma unroll
  for (int i = 0; i < 4; ++i)
    Wt[(long)(cb + ty * 4 + i) * ldo + kb + tx] = (bf16_t)t[tx][ty * 4 + i];
}

__device__ __forceinline__ bf16x8 cvt2x4(float4 a, float4 b) {
  bf16x8 v;
  v[0] = (bf16_t)a.x; v[1] = (bf16_t)a.y; v[2] = (bf16_t)a.z; v[3] = (bf16_t)a.w;
  v[4] = (bf16_t)b.x; v[5] = (bf16_t)b.y; v[6] = (bf16_t)b.z; v[7] = (bf16_t)b.w;
  return v;
}

__global__ __launch_bounds__(256) void k_prep(PrepArgs p) {
  __shared__ alignas(16) char psh[16384];
  float (*tsh)[33] = (float (*)[33])psh;
  const int blk = blockIdx.x;
  if (blk < PR_C0) {
    prep_cast(p.features, p.featBF, blk);
  } else if (blk < PR_C1) {
    prep_cast(p.geometry, p.geomBF, blk - PR_C0);
  } else if (blk < PR_WQ) {
    prep_transpose(p.wq, p.WqkvT, 512, 512, 512, blk - PR_C1, tsh);
  } else if (blk < PR_WK) {
    prep_transpose(p.wk, p.WqkvT + 512 * 512, 512, 512, 512, blk - PR_WQ, tsh);
  } else if (blk < PR_WV) {
    prep_transpose(p.wv, p.WqkvT + 1024 * 512, 512, 512, 512, blk - PR_WK, tsh);
  } else if (blk < PR_WO) {
    prep_transpose(p.wo, p.WoT, 512, 512, 512, blk - PR_WV, tsh);
  } else if (blk < PR_OP) {
    prep_transpose(p.op_w, p.OpT, 512, 512, 512, blk - PR_WO, tsh);
  } else if (blk < PR_GVT) {
    prep_transpose(p.gv_w, p.GqvT2 + 128 * 128, 128, 512, 128, blk - PR_OP, tsh);
  } else if (blk < PR_WEFF) {
    // WeffT[g][h] = sum_f gk_w[g][f]*gq_w[h][f]  (64x64 tile per block)
    bf16_t (*As)[64] = (bf16_t (*)[64])psh;
    bf16_t (*Bs)[64] = (bf16_t (*)[64])(psh + 8192);
    const int wb = blk - PR_GVT;
    const int gBrow = (wb >> 1) * 64;
    const int hBcol = (wb & 1) * 64;
    const int tid = threadIdx.x;
    const int w4 = tid >> 6, lane = tid & 63;
    const int lr = lane & 15, lg = lane >> 4;
    const int wr = w4 >> 1, wc = w4 & 1;
    const int srow = tid >> 2, scol = (tid & 3) << 4;
    f32x4 zero = {0.f, 0.f, 0.f, 0.f};
    f32x4 acc[2][2] = {{zero, zero}, {zero, zero}};
    for (int f0 = 0; f0 < 512; f0 += 64) {
#pragma unroll
      for (int hh = 0; hh < 2; ++hh) {
        const long offA = (long)(gBrow + srow) * 512 + f0 + scol + hh * 8;
        float4 a0 = *(const float4*)(p.gk_w + offA);
        float4 a1 = *(const float4*)(p.gk_w + offA + 4);
        *(bf16x8*)(&As[srow][scol + hh * 8]) = cvt2x4(a0, a1);
        const long offB = (long)(hBcol + srow) * 512 + f0 + scol + hh * 8;
        float4 b0 = *(const float4*)(p.gq_w + offB);
        float4 b1 = *(const float4*)(p.gq_w + offB + 4);
        *(bf16x8*)(&Bs[srow][scol + hh * 8]) = cvt2x4(b0, b1);
      }
      __syncthreads();
#pragma unroll
      for (int ks = 0; ks < 2; ++ks) {
        bf16x8 a[2], b[2];
#pragma unroll
        for (int i = 0; i < 2; ++i) {
          a[i] = *(const bf16x8*)(&As[wr * 32 + i * 16 + lr][ks * 32 + lg * 8]);
          b[i] = *(const bf16x8*)(&Bs[wc * 32 + i * 16 + lr][ks * 32 + lg * 8]);
        }
#pragma unroll
        for (int mf = 0; mf < 2; ++mf)
#pragma unroll
          for (int nf = 0; nf < 2; ++nf)
            acc[mf][nf] = MFMA16(a[mf], b[nf], acc[mf][nf]);
      }
      __syncthreads();
    }
#pragma unroll
    for (int mf = 0; mf < 2; ++mf)
#pragma unroll
      for (int nf = 0; nf < 2; ++nf)
#pragma unroll
        for (int rg = 0; rg < 4; ++rg) {
          const int row = gBrow + wr * 32 + mf * 16 + lg * 4 + rg;
          const int col = hBcol + wc * 32 + nf * 16 + lr;
          p.GqvT2[(long)row * 128 + col] = (bf16_t)acc[mf][nf][rg];
        }
  } else if (blk < PR_BEFF) {
    const int g = threadIdx.x;
    if (g < 128) {
      float s = 0.f;
      for (int f = 0; f < 512; ++f) s = fmaf(p.gq_b[f], p.gk_w[(long)g * 512 + f], s);
      p.gqvb2[g] = s;
    }
  } else if (blk < PR_B1) {
    int i = (blk - PR_BEFF) * 256 + threadIdx.x;
    p.bqkv[i] = i < 512 ? p.bq[i] : (i < 1024 ? p.bk[i - 512] : p.bv[i - 1024]);
  } else if (blk < PR_B2) {
    int i = (blk - PR_B1) * 256 + threadIdx.x;
    p.gqvb2[128 + i] = p.gv_b[i];
  } else {
    int i = (blk - PR_B2) * 256 + threadIdx.x;
    float d = (i + 0.5f) * (16.f / 4096.f);
    float s = 0.f;
#pragma unroll
    for (int h = 0; h < 8; ++h) s += p.d2b[h];
    s *= 0.125f;
#pragma unroll
    for (int j = 0; j < 8; ++j) {
      float w2 = 0.f;
#pragma unroll
      for (int h = 0; h < 8; ++h) w2 += p.d2w[j * 8 + h];
      s = fmaf(gelu_tanh(fmaf(d, p.d1w[j], p.d1b[j])), w2 * 0.125f, s);
    }
    p.dlut[i] = s;
  }
}

// ---------------- GEMM args ----------------
struct GemmArgs {
  const bf16_t* A; const bf16_t* Bt;
  const float* bias; const float* addSrc; const bf16_t* addSrcB;
  const float* coords; const float* lut;
  float* outF; bf16_t* outB;
  bf16_t* outT;      // if set: tiles with cBase>=vtileFrom write TRANSPOSED to outT
  int vtileFrom;
  long strideAb; long strideBb;
  int lda, ldb, K, ldout;
  float scale;
};

// ---- 128x128 core (plain epilogue + optional transposed V write) ----
__device__ __forceinline__ void gemm128_core(const GemmArgs& g, int mBase, int cBase,
                                             bf16_t (*As)[64], bf16_t (*Bs)[64]) {
  const int tid = threadIdx.x;
  const int w = tid >> 6, lane = tid & 63;
  const int lr = lane & 15, lg = lane >> 4;
  const int wr = w >> 1, wc = w & 1;
  const int batch = mBase >> 10;

  const int srow = lane >> 3;
  const int scol = (lane & 7) * 8;
  const bf16_t* Ag = g.A + (long)batch * g.strideAb +
                     (long)((mBase & 1023) + w * 32 + srow) * g.lda + scol;
  const bf16_t* Bg = g.Bt + (long)batch * g.strideBb +
                     (long)(cBase + w * 32 + srow) * g.ldb + scol;
  bf16_t* Al = &As[w * 32][0];
  bf16_t* Bl = &Bs[w * 32][0];

  f32x4 zero = {0.f, 0.f, 0.f, 0.f};
  f32x4 acc[4][4];
#pragma unroll
  for (int i = 0; i < 4; ++i)
#pragma unroll
    for (int j = 0; j < 4; ++j) acc[i][j] = zero;

  for (int k0 = 0; k0 < g.K; k0 += 64) {
#pragma unroll
    for (int is = 0; is < 4; ++is) {
      gl_lds16(Ag + (long)(is * 8) * g.lda + k0, Al + is * 8 * 64);
      gl_lds16(Bg + (long)(is * 8) * g.ldb + k0, Bl + is * 8 * 64);
    }
    __syncthreads();
#pragma unroll
    for (int ks = 0; ks < 2; ++ks) {
      bf16x8 a[4], b[4];
#pragma unroll
      for (int i = 0; i < 4; ++i) {
        a[i] = *(const bf16x8*)(&As[wr * 64 + i * 16 + lr][ks * 32 + lg * 8]);
        b[i] = *(const bf16x8*)(&Bs[wc * 64 + i * 16 + lr][ks * 32 + lg * 8]);
      }
#pragma unroll
      for (int mf = 0; mf < 4; ++mf)
#pragma unroll
        for (int nf = 0; nf < 4; ++nf)
          acc[mf][nf] = MFMA16(a[mf], b[nf], acc[mf][nf]);
    }
    __syncthreads();
  }

  const int c0 = cBase + wc * 64;
  float bias4[4];
#pragma unroll
  for (int nf = 0; nf < 4; ++nf)
    bias4[nf] = g.bias ? g.bias[c0 + nf * 16 + lr] : 0.f;
  const bool vtile = (g.outT != nullptr) && (cBase >= g.vtileFrom);
#pragma unroll
  for (int mf = 0; mf < 4; ++mf) {
    const int r0 = mBase + wr * 64 + mf * 16 + lg * 4;
    const int r0b = r0 & 1023;
#pragma unroll
    for (int nf = 0; nf < 4; ++nf) {
      const int c = c0 + nf * 16 + lr;
      if (vtile) {
        bf16x4v vv;
#pragma unroll
        for (int rg = 0; rg < 4; ++rg)
          vv[rg] = (bf16_t)(acc[mf][nf][rg] * g.scale + bias4[nf]);
        *(bf16x4v*)(&g.outT[((long)batch * 512 + (c - g.vtileFrom)) * 1024 + r0b]) = vv;
      } else {
#pragma unroll
        for (int rg = 0; rg < 4; ++rg) {
          const int r = r0 + rg;
          float v = acc[mf][nf][rg] * g.scale + bias4[nf];
          if (g.addSrc) v += g.addSrc[(long)r * g.ldout + c];
          const long oi = (long)r * g.ldout + c;
          if (g.outF) g.outF[oi] = v;
          if (g.outB) g.outB[oi] = (bf16_t)v;
        }
      }
    }
  }
}

// dual-role 128x128 GEMM (flattened: 768 QKV blocks + 320 GQV2 blocks)
__global__ __launch_bounds__(256) void k_gemm128_dual(GemmArgs g1, GemmArgs g2) {
  __shared__ alignas(16) bf16_t As[128][64];
  __shared__ alignas(16) bf16_t Bs[128][64];
  const int bx = blockIdx.x;
  if (bx < 768) {
    gemm128_core(g1, (bx / 12) * 128, (bx % 12) * 128, As, Bs);
  } else {
    const int i = bx - 768;
    gemm128_core(g2, (i / 5) * 128, (i % 5) * 128, As, Bs);
  }
}

// ---- 128x128 core, dist-LUT + exp2 epilogue -> bf16 Pun (unnormalized p) ----
__device__ __forceinline__ void gemm128_dist(const GemmArgs& g, int mBase, int cBase,
                                             char* smemc) {
  bf16_t (*As)[64] = (bf16_t (*)[64])smemc;
  bf16_t (*Bs)[64] = (bf16_t (*)[64])(smemc + 16384);
  bf16_t* Lut = (bf16_t*)(smemc + 32768);
  const int tid = threadIdx.x;
  const int w = tid >> 6, lane = tid & 63;
  const int lr = lane & 15, lg = lane >> 4;
  const int wr = w >> 1, wc = w & 1;
  const int batch = mBase >> 10;

  {
    const float4* src = (const float4*)g.lut;
#pragma unroll
    for (int i = 0; i < 4; ++i) {
      float4 v = src[tid + i * 256];
      bf16x4v o;
      o[0] = (bf16_t)(v.x * LOG2E); o[1] = (bf16_t)(v.y * LOG2E);
      o[2] = (bf16_t)(v.z * LOG2E); o[3] = (bf16_t)(v.w * LOG2E);
      ((bf16x4v*)Lut)[tid + i * 256] = o;
    }
  }

  const int srow = lane >> 3;
  const int scol = (lane & 7) * 8;
  const bf16_t* Ag = g.A + (long)batch * g.strideAb +
                     (long)((mBase & 1023) + w * 32 + srow) * g.lda + scol;
  const bf16_t* Bg = g.Bt + (long)batch * g.strideBb +
                     (long)(cBase + w * 32 + srow) * g.ldb + scol;
  bf16_t* Al = &As[w * 32][0];
  bf16_t* Bl = &Bs[w * 32][0];

  f32x4 zero = {0.f, 0.f, 0.f, 0.f};
  f32x4 acc[4][4];
#pragma unroll
  for (int i = 0; i < 4; ++i)
#pragma unroll
    for (int j = 0; j < 4; ++j) acc[i][j] = zero;

  for (int k0 = 0; k0 < g.K; k0 += 64) {
#pragma unroll
    for (int is = 0; is < 4; ++is) {
      gl_lds16(Ag + (long)(is * 8) * g.lda + k0, Al + is * 8 * 64);
      gl_lds16(Bg + (long)(is * 8) * g.ldb + k0, Bl + is * 8 * 64);
    }
    __syncthreads();
#pragma unroll
    for (int ks = 0; ks < 2; ++ks) {
      bf16x8 a[4], b[4];
#pragma unroll
      for (int i = 0; i < 4; ++i) {
        a[i] = *(const bf16x8*)(&As[wr * 64 + i * 16 + lr][ks * 32 + lg * 8]);
        b[i] = *(const bf16x8*)(&Bs[wc * 64 + i * 16 + lr][ks * 32 + lg * 8]);
      }
#pragma unroll
      for (int mf = 0; mf < 4; ++mf)
#pragma unroll
        for (int nf = 0; nf < 4; ++nf)
          acc[mf][nf] = MFMA16(a[mf], b[nf], acc[mf][nf]);
    }
    __syncthreads();
  }

  const int c0 = cBase + wc * 64;
  float ckx[4], cky[4], ckz[4];
#pragma unroll
  for (int nf = 0; nf < 4; ++nf) {
    const float* ck = g.coords + ((long)batch * 1024 + c0 + nf * 16 + lr) * 3;
    ckx[nf] = ck[0]; cky[nf] = ck[1]; ckz[nf] = ck[2];
  }
#pragma unroll
  for (int mf = 0; mf < 4; ++mf) {
    const int r0 = mBase + wr * 64 + mf * 16 + lg * 4;
    float cqx[4], cqy[4], cqz[4];
#pragma unroll
    for (int rg = 0; rg < 4; ++rg) {
      const float* cq = g.coords + ((long)batch * 1024 + ((r0 + rg) & 1023)) * 3;
      cqx[rg] = cq[0]; cqy[rg] = cq[1]; cqz[rg] = cq[2];
    }
#pragma unroll
    for (int nf = 0; nf < 4; ++nf) {
      const int c = c0 + nf * 16 + lr;
#pragma unroll
      for (int rg = 0; rg < 4; ++rg) {
        const int r = r0 + rg;
        float v = acc[mf][nf][rg] * g.scale;  // scale = 0.125*log2e
        float dx = cqx[rg] - ckx[nf], dy = cqy[rg] - cky[nf], dz = cqz[rg] - ckz[nf];
        float d = sqrtf(fmaxf(dx * dx + dy * dy + dz * dz, 1e-12f));
        int idx = (int)(d * 256.f);
        idx = idx > 4095 ? 4095 : idx;
        g.outB[(long)r * g.ldout + c] = (bf16_t)exp2f(v + (float)Lut[idx]);
      }
    }
  }
}

// ---- flash attention core, QBLK=128 (2 q-frags/wave); l via ones-MFMA ----
// P relay buffer: stride 64B with XOR swizzle s=(q&6)<<3 (bits 4-5 only):
// write bf16x4 at q*64 + ((kh*32+kg*8)^s); read bf16x8 at q*64 + ((lg*16)^s).
// Bandwidth-minimal on both sides (2-way alias only); total LDS 40960 -> 4/CU.
__device__ __forceinline__ void flash_core(const bf16_t* __restrict__ QKV,
                                           const bf16_t* __restrict__ Vt,
                                           bf16_t* __restrict__ fatt,
                                           int qx, int bh, char* smemc) {
  bf16_t (*Ks)[64][64] = (bf16_t (*)[64][64])smemc;            // 16 KB
  bf16_t (*Vs)[64][64] = (bf16_t (*)[64][64])(smemc + 16384);  // 16 KB
  char* Plb = smemc + 32768;                                   // 8 KB (4w x 2f x 16x32)
  const int wave = threadIdx.x >> 6, lane = threadIdx.x & 63;
  const int lr = lane & 15, lg = (lane >> 4) & 3;
  const int b = bh >> 3, h = bh & 7;
  const int qbase = qx * 128 + wave * 32;

  const bf16_t* Qb = QKV + (long)b * 1024 * 1536 + h * 64;
  const bf16_t* Kb = Qb + 512;
  const bf16_t* Vg = Vt + ((long)b * 512 + h * 64) * 1024;

  constexpr float SCL = 0.18033688011112042f;  // 0.125 * log2(e)
  bf16x8 q_[2][2];
#pragma unroll
  for (int qf = 0; qf < 2; ++qf)
#pragma unroll
    for (int dh = 0; dh < 2; ++dh) {
      bf16x8 raw = *(const bf16x8*)(Qb + (long)(qbase + qf * 16 + lr) * 1536 +
                                    dh * 32 + lg * 8);
#pragma unroll
      for (int j = 0; j < 8; ++j) q_[qf][dh][j] = (bf16_t)((float)raw[j] * SCL);
    }
  bf16x8 onesb;
#pragma unroll
  for (int j = 0; j < 8; ++j) onesb[j] = (bf16_t)1.0f;

  const int srow = lane >> 3;
  const int scol = (((lane & 7) ^ srow) << 3);
  const bf16_t* KgB = Kb + (long)(wave * 16 + srow) * 1536 + scol;
  const bf16_t* VgB = Vg + (long)(wave * 16 + srow) * 1024 + scol;

  auto stage = [&](int buf, int kt) {
#pragma unroll
    for (int i = 0; i < 2; ++i) {
      gl_lds16(KgB + (long)(kt + i * 8) * 1536, &Ks[buf][wave * 16 + i * 8][0]);
      gl_lds16(VgB + (long)(i * 8) * 1024 + kt, &Vs[buf][wave * 16 + i * 8][0]);
    }
  };

  f32x4 zero = {0.f, 0.f, 0.f, 0.f};
  f32x4 oacc[2][4] = {{zero, zero, zero, zero}, {zero, zero, zero, zero}};
  f32x4 oL[2] = {zero, zero};
  const int swz = (lr & 7) << 4;        // K/V tile swizzle
  const int swp = (lr & 6) << 3;        // P buffer swizzle (bits 4-5)
  char* PlW = Plb + wave * 2048;

  stage(0, 0);
  asm volatile("s_waitcnt vmcnt(0)" ::: "memory");
  __syncthreads();

  auto tile = [&](const int buf, int t) __attribute__((always_inline)) {
    if (t < 15) stage(buf ^ 1, (t + 1) * 64);
    const char* KB = (const char*)&Ks[buf][0][0];
    const char* VB = (const char*)&Vs[buf][0][0];
#pragma unroll
    for (int kk = 0; kk < 2; ++kk) {
      f32x4 S[2][2];
      __builtin_amdgcn_s_setprio(1);
#pragma unroll
      for (int kh = 0; kh < 2; ++kh) {
        const int row = kk * 32 + kh * 16 + lr;
        bf16x8 k0 = *(const bf16x8*)(KB + row * 128 + ((lg * 16) ^ swz));
        bf16x8 k1 = *(const bf16x8*)(KB + row * 128 + ((64 + lg * 16) ^ swz));
#pragma unroll
        for (int qf = 0; qf < 2; ++qf) {
          f32x4 tt = MFMA16(k0, q_[qf][0], zero);
          S[qf][kh] = MFMA16(k1, q_[qf][1], tt);
        }
      }
      __builtin_amdgcn_s_setprio(0);
#pragma unroll
      for (int qf = 0; qf < 2; ++qf)
#pragma unroll
        for (int kh = 0; kh < 2; ++kh) {
          bf16x4v pp;
#pragma unroll
          for (int r = 0; r < 4; ++r) pp[r] = (bf16_t)exp2f(S[qf][kh][r]);
          *(bf16x4v*)(PlW + qf * 1024 + lr * 64 + ((kh * 32 + lg * 8) ^ swp)) = pp;
        }
      asm volatile("s_waitcnt lgkmcnt(0)" ::: "memory");
      const bf16x8 pa0 = *(const bf16x8*)(PlW + lr * 64 + ((lg * 16) ^ swp));
      const bf16x8 pa1 = *(const bf16x8*)(PlW + 1024 + lr * 64 + ((lg * 16) ^ swp));
      __builtin_amdgcn_s_setprio(1);
#pragma unroll
      for (int ct = 0; ct < 4; ++ct) {
        const int vrow = ct * 16 + lr;
        bf16x8 vf = *(const bf16x8*)(VB + vrow * 128 + ((kk * 64 + lg * 16) ^ swz));
        oacc[0][ct] = MFMA16(pa0, vf, oacc[0][ct]);
        oacc[1][ct] = MFMA16(pa1, vf, oacc[1][ct]);
      }
      oL[0] = MFMA16(pa0, onesb, oL[0]);
      oL[1] = MFMA16(pa1, onesb, oL[1]);
      __builtin_amdgcn_s_setprio(0);
    }
    asm volatile("s_waitcnt vmcnt(0)" ::: "memory");
    __syncthreads();
  };

  for (int tt = 0; tt < 8; ++tt) {
    tile(0, tt * 2);
    tile(1, tt * 2 + 1);
  }

#pragma unroll
  for (int qf = 0; qf < 2; ++qf)
#pragma unroll
    for (int r = 0; r < 4; ++r) {
      float inv = 1.f / oL[qf][r];
      int q = qbase + qf * 16 + lg * 4 + r;
      bf16_t* orow = fatt + ((long)b * 1024 + q) * 512 + h * 64;
#pragma unroll
      for (int ct = 0; ct < 4; ++ct)
        orow[ct * 16 + lr] = (bf16_t)(oacc[qf][ct][r] * inv);
    }
}

// ---- fused: gsc (blocks 0..511, K=128 low-rank) + flash QBLK=128 (512..1023) --
__global__ __launch_bounds__(256) void k_gsc_flash(GemmArgs g,
                                                   const bf16_t* __restrict__ QKV,
                                                   const bf16_t* __restrict__ Vt,
                                                   bf16_t* __restrict__ fatt) {
  __shared__ alignas(16) char smem[40960];
  const int bx = blockIdx.x;
  if (bx < 512) {
    gemm128_dist(g, (bx >> 3) * 128, (bx & 7) * 128, smem);
  } else {
    const int fid = bx - 512;
    flash_core(QKV, Vt, fatt, fid & 7, fid >> 3, smem);
  }
}

// ---- 64x64 tile K-loop: 4 waves, each a 32x32 quadrant (acc[2][2]) ----
template <int RSUM>
__device__ __forceinline__ void m64_loop(const GemmArgs& g, int mBase, int cBase,
                                         bf16_t (*As)[64], bf16_t (*Bs)[64],
                                         f32x4 (*acc)[2], f32x4* lacc) {
  const int tid = threadIdx.x;
  const int w = tid >> 6, lane = tid & 63;
  const int lr = lane & 15, lg = lane >> 4;
  const int wr = w >> 1, wc = w & 1;
  const int batch = mBase >> 10;

  const int srow = lane >> 3;
  const int scol = (lane & 7) * 8;
  const bf16_t* Ag = g.A + (long)batch * g.strideAb +
                     (long)((mBase & 1023) + w * 16 + srow) * g.lda + scol;
  const bf16_t* Bg = g.Bt + (long)batch * g.strideBb +
                     (long)(cBase + w * 16 + srow) * g.ldb + scol;
  bf16_t* Al = &As[w * 16][0];
  bf16_t* Bl = &Bs[w * 16][0];

  bf16x8 onesb;
#pragma unroll
  for (int j = 0; j < 8; ++j) onesb[j] = (bf16_t)1.0f;

  for (int k0 = 0; k0 < g.K; k0 += 64) {
#pragma unroll
    for (int is = 0; is < 2; ++is) {
      gl_lds16(Ag + (long)(is * 8) * g.lda + k0, Al + is * 8 * 64);
      gl_lds16(Bg + (long)(is * 8) * g.ldb + k0, Bl + is * 8 * 64);
    }
    __syncthreads();
#pragma unroll
    for (int ks = 0; ks < 2; ++ks) {
      bf16x8 a[2], b[2];
#pragma unroll
      for (int i = 0; i < 2; ++i) {
        a[i] = *(const bf16x8*)(&As[wr * 32 + i * 16 + lr][ks * 32 + lg * 8]);
        b[i] = *(const bf16x8*)(&Bs[wc * 32 + i * 16 + lr][ks * 32 + lg * 8]);
      }
#pragma unroll
      for (int mf = 0; mf < 2; ++mf)
#pragma unroll
        for (int nf = 0; nf < 2; ++nf)
          acc[mf][nf] = MFMA16(a[mf], b[nf], acc[mf][nf]);
      if constexpr (RSUM) {
#pragma unroll
        for (int mf = 0; mf < 2; ++mf)
          lacc[mf] = MFMA16(a[mf], onesb, lacc[mf]);
      }
    }
    __syncthreads();
  }
}

// ---- plain 64x64 GEMM (4 blocks/CU for the latency-bound tail) ----
__global__ __launch_bounds__(256) void k_gemm_m64(GemmArgs g) {
  __shared__ alignas(16) bf16_t As[64][64];
  __shared__ alignas(16) bf16_t Bs[64][64];
  const int tid = threadIdx.x;
  const int w = tid >> 6, lane = tid & 63;
  const int lr = lane & 15, lg = lane >> 4;
  const int wr = w >> 1, wc = w & 1;
  const int mBase = blockIdx.y * 64, cBase = blockIdx.x * 64;

  f32x4 zero = {0.f, 0.f, 0.f, 0.f};
  f32x4 acc[2][2] = {{zero, zero}, {zero, zero}};
  m64_loop<0>(g, mBase, cBase, As, Bs, acc, nullptr);

  const int c0 = cBase + wc * 32;
  float bias2[2];
#pragma unroll
  for (int nf = 0; nf < 2; ++nf)
    bias2[nf] = g.bias ? g.bias[c0 + nf * 16 + lr] : 0.f;
#pragma unroll
  for (int mf = 0; mf < 2; ++mf) {
    const int r0 = mBase + wr * 32 + mf * 16 + lg * 4;
#pragma unroll
    for (int nf = 0; nf < 2; ++nf) {
      const int c = c0 + nf * 16 + lr;
#pragma unroll
      for (int rg = 0; rg < 4; ++rg) {
        const int r = r0 + rg;
        float v = acc[mf][nf][rg] * g.scale + bias2[nf];
        const long oi = (long)r * g.ldout + c;
        if (g.outF) g.outF[oi] = v;
        if (g.outB) g.outB[oi] = (bf16_t)v;
      }
    }
  }
}

// ---- fused comb: combB = (Pun @ GV)/rowsum(Pun) + fatt @ Wo + bo ----
__global__ __launch_bounds__(256) void k_comb(GemmArgs gF, GemmArgs gG,
                                              bf16_t* __restrict__ outB) {
  __shared__ alignas(16) bf16_t As[64][64];
  __shared__ alignas(16) bf16_t Bs[64][64];
  const int tid = threadIdx.x;
  const int w = tid >> 6, lane = tid & 63;
  const int lr = lane & 15, lg = lane >> 4;
  const int wr = w >> 1, wc = w & 1;
  const int mBase = blockIdx.y * 64, cBase = blockIdx.x * 64;

  f32x4 zero = {0.f, 0.f, 0.f, 0.f};
  f32x4 acc1[2][2] = {{zero, zero}, {zero, zero}};
  f32x4 acc2[2][2] = {{zero, zero}, {zero, zero}};
  f32x4 lacc[2] = {zero, zero};
  m64_loop<0>(gF, mBase, cBase, As, Bs, acc1, nullptr);
  m64_loop<1>(gG, mBase, cBase, As, Bs, acc2, lacc);

  const int c0 = cBase + wc * 32;
  float bias2[2];
#pragma unroll
  for (int nf = 0; nf < 2; ++nf)
    bias2[nf] = gF.bias[c0 + nf * 16 + lr];
#pragma unroll
  for (int mf = 0; mf < 2; ++mf) {
    const int r0 = mBase + wr * 32 + mf * 16 + lg * 4;
    float linv[4];
#pragma unroll
    for (int rg = 0; rg < 4; ++rg) linv[rg] = 1.f / lacc[mf][rg];
#pragma unroll
    for (int nf = 0; nf < 2; ++nf) {
      const int c = c0 + nf * 16 + lr;
#pragma unroll
      for (int rg = 0; rg < 4; ++rg) {
        const int r = r0 + rg;
        float v = acc2[mf][nf][rg] * linv[rg] + acc1[mf][nf][rg] + bias2[nf];
        outB[(long)r * 512 + c] = (bf16_t)v;
      }
    }
  }
}

// ---------------- launch ----------------
extern "C" void kernel_launch(void* const* d_in, const int* in_sizes, int n_in,
                              void* d_out, int out_size, void* d_ws, size_t ws_size,
                              hipStream_t stream) {
  const float* features = (const float*)d_in[0];
  const float* geometry = (const float*)d_in[1];
  const float* coords   = (const float*)d_in[2];
  const float* wq = (const float*)d_in[3];  const float* bq = (const float*)d_in[4];
  const float* wk = (const float*)d_in[5];  const float* bk = (const float*)d_in[6];
  const float* wv = (const float*)d_in[7];  const float* bv = (const float*)d_in[8];
  const float* wo = (const float*)d_in[9];  const float* bo = (const float*)d_in[10];
  const float* gq_w = (const float*)d_in[11]; const float* gq_b = (const float*)d_in[12];
  const float* gk_w = (const float*)d_in[13]; const float* gk_b = (const float*)d_in[14];
  const float* gv_w = (const float*)d_in[15]; const float* gv_b = (const float*)d_in[16];
  const float* d1_w = (const float*)d_in[17]; const float* d1_b = (const float*)d_in[18];
  const float* d2_w = (const float*)d_in[19]; const float* d2_b = (const float*)d_in[20];
  const float* op_w = (const float*)d_in[21]; const float* op_b = (const float*)d_in[22];
  (void)gk_b;  // row-constant score term: cancels under softmax normalization

  // ---- workspace carve ----
  size_t off = 0;
  auto carve = [&](size_t bytes) {
    void* p = (char*)d_ws + off;
    off += (bytes + 255) & ~(size_t)255;
    return p;
  };
  bf16_t* featBF = (bf16_t*)carve((size_t)M_ * F_ * 2);
  bf16_t* geomBF = (bf16_t*)carve((size_t)M_ * 128 * 2);
  bf16_t* WqkvT  = (bf16_t*)carve((size_t)1536 * 512 * 2);
  bf16_t* GqvT2  = (bf16_t*)carve((size_t)640 * 128 * 2);  // [0:128)=WeffT, [128:640)=gv^T
  bf16_t* WoT    = (bf16_t*)carve((size_t)512 * 512 * 2);
  bf16_t* OpT    = (bf16_t*)carve((size_t)512 * 512 * 2);
  float*  bqkv   = (float*)carve(1536 * 4);
  float*  gqvb2  = (float*)carve(640 * 4);
  float*  dlut   = (float*)carve(4096 * 4);
  bf16_t* QKV    = (bf16_t*)carve((size_t)M_ * 1536 * 2);
  bf16_t* GQeff  = (bf16_t*)carve((size_t)M_ * 128 * 2);
  bf16_t* Vt     = (bf16_t*)carve((size_t)B_ * 512 * 1024 * 2);
  bf16_t* GVt    = (bf16_t*)carve((size_t)B_ * 512 * 1024 * 2);
  bf16_t* Pun    = (bf16_t*)carve((size_t)M_ * 1024 * 2);
  bf16_t* fatt   = (bf16_t*)carve((size_t)M_ * 512 * 2);
  bf16_t* combB  = (bf16_t*)carve((size_t)M_ * 512 * 2);
  if (off > ws_size) return;

  // 0) merged prep (WeffT + beff folded in)
  PrepArgs p;
  p.features = features; p.geometry = geometry;
  p.wq = wq; p.wk = wk; p.wv = wv; p.wo = wo; p.op_w = op_w;
  p.gq_w = gq_w; p.gk_w = gk_w; p.gv_w = gv_w;
  p.bq = bq; p.bk = bk; p.bv = bv; p.gq_b = gq_b; p.gv_b = gv_b;
  p.d1w = d1_w; p.d1b = d1_b; p.d2w = d2_w; p.d2b = d2_b;
  p.featBF = featBF; p.geomBF = geomBF; p.WqkvT = WqkvT; p.GqvT2 = GqvT2;
  p.WoT = WoT; p.OpT = OpT;
  p.bqkv = bqkv; p.gqvb2 = gqvb2; p.dlut = dlut;
  k_prep<<<PR_TOTAL, 256, 0, stream>>>(p);

  auto mk = [](const bf16_t* A, long sAb, int lda, const bf16_t* Bt, long sBb, int ldb,
               int K, const float* bias, const float* addSrc, const bf16_t* addSrcB,
               float* outF, bf16_t* outB, int ldout, float scale,
               const float* coords, const float* lut, bf16_t* outT, int vtileFrom) {
    GemmArgs g;
    g.A = A; g.Bt = Bt; g.bias = bias; g.addSrc = addSrc; g.addSrcB = addSrcB;
    g.coords = coords; g.lut = lut; g.outF = outF; g.outB = outB; g.outT = outT;
    g.vtileFrom = vtileFrom;
    g.strideAb = sAb; g.strideBb = sBb; g.lda = lda; g.ldb = ldb;
    g.K = K; g.ldout = ldout; g.scale = scale;
    return g;
  };

  // 1) QKV (768 blocks) + [GQeff|GV] (320 blocks); V/GV written TRANSPOSED
  k_gemm128_dual<<<1088, 256, 0, stream>>>(
      mk(featBF, (long)1024 * 512, 512, WqkvT, 0, 512, 512,
         bqkv, nullptr, nullptr, nullptr, QKV, 1536, 1.f, nullptr, nullptr, Vt, 1024),
      mk(geomBF, (long)1024 * 128, 128, GqvT2, 0, 128, 128,
         gqvb2, nullptr, nullptr, nullptr, GQeff, 128, 1.f, nullptr, nullptr, GVt, 128));
  // 2) fused: Pun = exp2(GQeff.geom^T*scl + lut) [K=128] + flash (QBLK=128)
  k_gsc_flash<<<1024, 256, 0, stream>>>(
      mk(GQeff, (long)1024 * 128, 128, geomBF, (long)1024 * 128, 128, 128,
         nullptr, nullptr, nullptr, nullptr, Pun, 1024, 0.125f * LOG2E,
         coords, dlut, nullptr, 1 << 30),
      QKV, Vt, fatt);
  // 3) combB = (Pun @ GV)/rowsum(Pun) + fatt @ wo + bo  (fused, 64x64 tiles)
  k_comb<<<dim3(8, 128), 256, 0, stream>>>(
      mk(fatt, (long)1024 * 512, 512, WoT, 0, 512, 512,
         bo, nullptr, nullptr, nullptr, nullptr, 512, 1.f, nullptr, nullptr,
         nullptr, 1 << 30),
      mk(Pun, (long)1024 * 1024, 1024, GVt, (long)512 * 1024, 1024, 1024,
         nullptr, nullptr, nullptr, nullptr, nullptr, 512, 1.f, nullptr, nullptr,
         nullptr, 1 << 30),
      combB);
  // 4) out = combB @ op_w + op_b
  k_gemm_m64<<<dim3(8, 128), 256, 0, stream>>>(
      mk(combB, (long)1024 * 512, 512, OpT, 0, 512, 512,
         op_b, nullptr, nullptr, (float*)d_out, nullptr, 512, 1.f, nullptr, nullptr,
         nullptr, 1 << 30));
}